// Round 3
// baseline (14379.291 us; speedup 1.0000x reference)
//
#include <hip/hip_runtime.h>
#include <math.h>

#define NWG 256
#define TPB 256

static constexpr int Bc=128, Ic=256, Hc=512, NCc=16, Tc=24, Mc=14;
static constexpr int Y_SZ  = Bc*NCc*Tc;     // 49152
static constexpr int P_OFF = Y_SZ;          // 49152
static constexpr int N_OFF = Y_SZ + Bc;     // 49280

// ws layout (floats) -- total 360448 floats = 1.375 MiB (must stay << 3.8 MB proven)
static constexpr int XSZ    = Ic*Bc;                 // 32768 (one x time-slice, [i][b])
static constexpr int HSZ    = Hc*Bc;                 // 65536
static constexpr int PSZ    = Bc*Bc;                 // 16384
static constexpr int XS_OFF = 0;                     // xs[2][256][128]
static constexpr int HB_OFF = XS_OFF + 2*XSZ;        // hbuf[2][512][128]
static constexpr int SC_OFF = HB_OFF + 2*HSZ;        // stc[2][512][128]
static constexpr int HP_OFF = SC_OFF + 2*HSZ;        // hpp[2][128][128]

__device__ unsigned g_cnt = 0;
__device__ unsigned g_gen = 0;

__device__ __forceinline__ float sigm(float v){ return 1.0f/(1.0f+expf(-v)); }

// Cross-workgroup data: system-scope relaxed atomics => sc0 sc1 accesses,
// coherent at the Infinity Cache; no fence lowering is load-bearing for data.
__device__ __forceinline__ float gload(const float* p){
  return __hip_atomic_load(p, __ATOMIC_RELAXED, __HIP_MEMORY_SCOPE_SYSTEM);
}
__device__ __forceinline__ void gstore(float* p, float v){
  __hip_atomic_store(p, v, __ATOMIC_RELAXED, __HIP_MEMORY_SCOPE_SYSTEM);
}

// Generation barrier. Data coherence comes from the sc0/sc1 data path plus the
// vmcnt(0) drain the compiler emits at __syncthreads; the barrier itself only
// needs atomicity + compiler ordering, so atomics are RELAXED (no wbl2/inv).
__device__ __forceinline__ void gsync(){
  __syncthreads();
  if (threadIdx.x == 0) {
    asm volatile("" ::: "memory");
    unsigned gen  = __hip_atomic_load(&g_gen, __ATOMIC_RELAXED, __HIP_MEMORY_SCOPE_SYSTEM);
    unsigned prev = __hip_atomic_fetch_add(&g_cnt, 1u, __ATOMIC_RELAXED, __HIP_MEMORY_SCOPE_SYSTEM);
    if (prev == (unsigned)(NWG-1)) {
      __hip_atomic_store(&g_cnt, 0u, __ATOMIC_RELAXED, __HIP_MEMORY_SCOPE_SYSTEM);
      __hip_atomic_store(&g_gen, gen+1u, __ATOMIC_RELEASE, __HIP_MEMORY_SCOPE_SYSTEM);
    } else {
      while (__hip_atomic_load(&g_gen, __ATOMIC_RELAXED, __HIP_MEMORY_SCOPE_SYSTEM) == gen)
        __builtin_amdgcn_s_sleep(1);
    }
    asm volatile("" ::: "memory");
  }
  __syncthreads();
}

// Partial GEMV over this wave's k-slice: NGR groups of 8 k, depth-3 prefetch.
#define GEMM_BODY(NGR, DEC, SRC, WR, DWP)                                     \
  {                                                                           \
    float pv[3][8];                                                           \
    _Pragma("unroll")                                                         \
    for (int d=0; d<3; ++d) {                                                 \
      _Pragma("unroll")                                                       \
      for (int u=0; u<8; ++u) pv[d][u] = gload((SRC) + (d*8+u)*Bc);           \
    }                                                                         \
    _Pragma("unroll")                                                         \
    for (int it=0; it<(NGR); ++it) {                                          \
      const int cb = it % 3;                                                  \
      _Pragma("unroll")                                                       \
      for (int u=0; u<8; ++u) {                                               \
        const int kk = it*8+u;                                                \
        float hv = pv[cb][u];                                                 \
        _Pragma("unroll")                                                     \
        for (int r=0; r<16; ++r) part[r] = fmaf(hv, (WR)[r][kk], part[r]);    \
        if (DEC) dacc = fmaf(hv, (DWP)[kk], dacc);                            \
      }                                                                       \
      if (it+3 < (NGR)) {                                                     \
        _Pragma("unroll")                                                     \
        for (int u=0; u<8; ++u) pv[cb][u] = gload((SRC) + ((it+3)*8+u)*Bc);   \
      }                                                                       \
    }                                                                         \
  }

__global__ __launch_bounds__(TPB, 2) void act_lstm_kernel(
    const float* __restrict__ x,   const float* __restrict__ Wih,
    const float* __restrict__ Whh, const float* __restrict__ bih,
    const float* __restrict__ bhh, const float* __restrict__ hw,
    const float* __restrict__ hbp, const float* __restrict__ dw,
    const float* __restrict__ db,  float* __restrict__ out,
    float* __restrict__ ws)
{
  const int w    = blockIdx.x;
  const int tid  = threadIdx.x;
  const int lane = tid & 63;
  const int wid  = __builtin_amdgcn_readfirstlane(tid >> 6);
  const int gs   = w >> 1;          // j-group [0,128): owns j = gs*4..+3
  const int bh   = w & 1;           // batch half
  const int b    = bh*64 + lane;
  const int jb   = gs*4;
  const int jmine= jb + wid;
  const int jrow = jmine * Bc;
  const int kq   = wid * 128;       // k-quarter for h-GEMV
  const int iq   = wid * 64;        // i-quarter for x-GEMV
  const int nc   = gs & 15;         // decoder class for w<32 blocks

  float* xs   = ws + XS_OFF;
  float* hbuf = ws + HB_OFF;
  float* stc  = ws + SC_OFF;
  float* hpp  = ws + HP_OFF;

  __shared__ float lds_red[4*16*64];
  __shared__ float lds_hp[4*64];
  __shared__ float lds_hq[2*128];
  __shared__ float lds_pmh[128];
  __shared__ float lds_dec[4*64];
  __shared__ unsigned lds_u[2];

  const float* whp[16];
  const float* wip[16];
  float bsum[4];
  #pragma unroll
  for (int r=0; r<16; ++r) {
    const int grow = (r>>2)*512 + jb + (r&3);
    whp[r] = Whh + grow*Hc + kq;
    wip[r] = Wih + grow*Ic + iq;
  }
  #pragma unroll
  for (int ty=0; ty<4; ++ty) bsum[ty] = bih[ty*512 + jmine] + bhh[ty*512 + jmine];
  const float hwj = hw[jmine];
  const float hb0 = hbp[0];
  const float* dwq = dw + nc*Hc + kq;
  const float dbv  = db[nc];

  // -------- prologue: stage x[:,:,0] into xs[0][i][b] --------
  {
    int g = w*TPB + tid;
    if (g < XSZ) {
      int i = g >> 7, bb = g & 127;
      gstore(xs + i*Bc + bb, x[bb*(Ic*Tc) + i*Tc + 0]);
    }
  }
  gsync();

  // -------- persistent state --------
  float c = 0.f;
  float st_run=0.f, ct_run=0.f, prev_pm=0.f;
  float cumw=0.f, prevw=0.f, ntfw=0.f, rtvw=0.f, psumw=0.f;  // waves 0,1: b'=wid*64+lane
  bool  ntsetw=false;
  int   gt = 0;
  int   lastpar = 0;

  for (int t=0; t<Tc; ++t) {
    float xg[4];
    for (int mm=0;; ++mm) {
      float part[16];
      #pragma unroll
      for (int r=0; r<16; ++r) part[r]=0.f;
      float dacc = 0.f;

      // ---------- phase A: GEMVs ----------
      if (mm == 0) {
        const float* xsr = xs + (t&1)*XSZ + iq*Bc + b;
        GEMM_BODY(8, false, xsr, wip, dwq)
        #pragma unroll
        for (int r=0; r<16; ++r) lds_red[wid*1024 + r*64 + lane] = part[r];
        __syncthreads();
        #pragma unroll
        for (int ty=0; ty<4; ++ty) {
          float a0 = lds_red[0*1024 + (ty*4+wid)*64 + lane];
          float a1 = lds_red[1*1024 + (ty*4+wid)*64 + lane];
          float a2 = lds_red[2*1024 + (ty*4+wid)*64 + lane];
          float a3 = lds_red[3*1024 + (ty*4+wid)*64 + lane];
          xg[ty] = bsum[ty] + ((a0+a1)+(a2+a3));
        }
        __syncthreads();   // before lds_red reuse

        // stage next timestep's x slice (hidden under GEMV)
        if (t+1 < Tc) {
          int g = w*TPB + tid;
          if (g < XSZ) {
            int i = g >> 7, bb = g & 127;
            gstore(xs + ((t+1)&1)*XSZ + i*Bc + bb, x[bb*(Ic*Tc) + i*Tc + (t+1)]);
          }
        }

        #pragma unroll
        for (int r=0; r<16; ++r) part[r]=0.f;
        if (t > 0) {
          const float* hs = stc + lastpar*HSZ + kq*Bc + b;
          bool isdec = (w < 32);
          GEMM_BODY(16, isdec, hs, whp, dwq)
        }
      } else {
        const float* hs = hbuf + ((gt-1)&1)*HSZ + kq*Bc + b;
        GEMM_BODY(16, false, hs, whp, dwq)
      }

      // ---------- reduce partials across waves ----------
      #pragma unroll
      for (int r=0; r<16; ++r) lds_red[wid*1024 + r*64 + lane] = part[r];
      if (mm==0 && t>0 && w<32) lds_dec[wid*64+lane] = dacc;
      __syncthreads();
      float hacc[4];
      #pragma unroll
      for (int ty=0; ty<4; ++ty) {
        float a0 = lds_red[0*1024 + (ty*4+wid)*64 + lane];
        float a1 = lds_red[1*1024 + (ty*4+wid)*64 + lane];
        float a2 = lds_red[2*1024 + (ty*4+wid)*64 + lane];
        float a3 = lds_red[3*1024 + (ty*4+wid)*64 + lane];
        hacc[ty] = (a0+a1)+(a2+a3);
      }
      if (mm==0 && t>0 && w<32 && wid==0) {
        float y = ((lds_dec[lane]+lds_dec[64+lane])+(lds_dec[128+lane]+lds_dec[192+lane])) + dbv;
        out[(b*NCc + nc)*Tc + (t-1)] = y;
      }

      // ---------- LSTM cell (torch gate order i,f,g,o) ----------
      float ig = sigm(xg[0]+hacc[0]);
      float fg = sigm(xg[1]+hacc[1]);
      float gg = tanhf(xg[2]+hacc[2]);
      float og = sigm(xg[3]+hacc[3]);
      float cn = fg*c + ig*gg;
      float hn = og*tanhf(cn);

      gstore(hbuf + (gt&1)*HSZ + jrow + b, hn);
      gstore(stc  + (gt&1)*HSZ + jrow + b, st_run + (1.f - prev_pm)*hn); // st-candidate
      lds_hp[wid*64+lane] = hn*hwj;
      __syncthreads();
      if (wid == 0) {
        float h4 = (lds_hp[lane]+lds_hp[64+lane])+(lds_hp[128+lane]+lds_hp[192+lane]);
        gstore(hpp + (gt&1)*PSZ + gs*Bc + b, h4);
      }

      gsync();

      // ---------- phase B: replicated halting decision ----------
      // halt-dot sum parallelized over all 4 waves: wave = (gq=wid>>1, bh'=wid&1)
      {
        const int bh2 = wid & 1, gq = wid >> 1;
        const float* hp = hpp + (gt&1)*PSZ + gq*64*Bc + bh2*64 + lane;
        float s[8];
        #pragma unroll
        for (int u=0; u<8; ++u) s[u]=0.f;
        #pragma unroll
        for (int g8=0; g8<8; ++g8) {
          #pragma unroll
          for (int u=0; u<8; ++u) s[u] += gload(hp + (g8*8+u)*Bc);
        }
        lds_hq[gq*128 + bh2*64 + lane] = ((s[0]+s[1])+(s[2]+s[3]))+((s[4]+s[5])+(s[6]+s[7]));
      }
      __syncthreads();
      if (wid < 2) {
        float hpv = lds_hq[wid*64+lane] + lds_hq[128 + wid*64+lane];
        float pn = sigm(hpv + hb0);
        cumw += pn;
        int ok = __all(cumw >= 0.99f) ? 1 : 0;
        if (lane == 0) lds_u[wid] = (unsigned)ok;
        lds_pmh[wid*64+lane] = fminf(1.f, cumw);
      }
      __syncthreads();
      int finv = (((lds_u[0] & lds_u[1]) != 0u) || (mm == Mc-1)) ? 1 : 0;

      if (wid < 2) {   // nt/rt tracking for b' = wid*64+lane (replicated)
        float pmf = finv ? 1.f : fminf(1.f, cumw);
        if (!ntsetw && pmf >= 1.f) {
          ntfw = (float)mm;
          rtvw = (mm == 0) ? 0.f : (1.f - prevw);
          ntsetw = true;
        }
        prevw = pmf;
      }
      float pm = finv ? 1.f : lds_pmh[bh*64+lane];
      float ph = pm - prev_pm;
      st_run += ph*hn;
      ct_run += ph*cn;
      prev_pm = pm;
      if (finv) {
        c = ct_run;
        if (wid < 2) {
          psumw += ntfw + rtvw;
          if (w == 0) out[N_OFF + (wid*64+lane)*Tc + t] = ntfw;
          ntsetw=false; prevw=0.f; cumw=0.f; ntfw=0.f; rtvw=0.f;
        }
        st_run=0.f; ct_run=0.f; prev_pm=0.f;
        lastpar = gt & 1;
        ++gt;
        break;
      }
      c = cn;
      ++gt;
    }
  }

  // -------- epilogue: Y for t=23, P --------
  if (w < 32) {
    float da = 0.f;
    const float* hs = stc + lastpar*HSZ + kq*Bc + b;
    #pragma unroll
    for (int kk=0; kk<128; ++kk) da = fmaf(gload(hs + kk*Bc), dwq[kk], da);
    __syncthreads();
    lds_dec[wid*64+lane] = da;
    __syncthreads();
    if (wid == 0) {
      float y = ((lds_dec[lane]+lds_dec[64+lane])+(lds_dec[128+lane]+lds_dec[192+lane])) + dbv;
      out[(b*NCc + nc)*Tc + (Tc-1)] = y;
    }
  }
  if (w == 0 && wid < 2) out[P_OFF + wid*64 + lane] = psumw;
}

extern "C" void kernel_launch(void* const* d_in, const int* in_sizes, int n_in,
                              void* d_out, int out_size, void* d_ws, size_t ws_size,
                              hipStream_t stream) {
  const float* x   = (const float*)d_in[0];
  const float* Wih = (const float*)d_in[1];
  const float* Whh = (const float*)d_in[2];
  const float* bih = (const float*)d_in[3];
  const float* bhh = (const float*)d_in[4];
  const float* hw  = (const float*)d_in[5];
  const float* hb  = (const float*)d_in[6];
  const float* dwp = (const float*)d_in[7];
  const float* dbp = (const float*)d_in[8];
  float* out = (float*)d_out;
  float* ws  = (float*)d_ws;

  void* kargs[] = {(void*)&x, (void*)&Wih, (void*)&Whh, (void*)&bih, (void*)&bhh,
                   (void*)&hw, (void*)&hb, (void*)&dwp, (void*)&dbp, (void*)&out, (void*)&ws};
  hipLaunchCooperativeKernel((void*)act_lstm_kernel, dim3(NWG), dim3(TPB),
                             kargs, 0, stream);
}

// Round 4
// 6516.039 us; speedup vs baseline: 2.2068x; 2.2068x over previous
//
#include <hip/hip_runtime.h>
#include <math.h>

#define NWG 256
#define TPB 256

static constexpr int Bc=128, Ic=256, Hc=512, NCc=16, Tc=24, Mc=14;
static constexpr int Y_SZ  = Bc*NCc*Tc;     // 49152
static constexpr int P_OFF = Y_SZ;          // 49152
static constexpr int N_OFF = Y_SZ + Bc;     // 49280

// ws layout (floats) -- total 360448 floats = 1.375 MiB
static constexpr int XSZ    = Ic*Bc;                 // 32768 (one x time-slice, [i][b])
static constexpr int HSZ    = Hc*Bc;                 // 65536
static constexpr int PSZ    = Bc*Bc;                 // 16384
static constexpr int XS_OFF = 0;                     // xs[2][256][128]
static constexpr int HB_OFF = XS_OFF + 2*XSZ;        // hbuf[2][512][128]
static constexpr int SC_OFF = HB_OFF + 2*HSZ;        // stc[2][512][128]
static constexpr int HP_OFF = SC_OFF + 2*HSZ;        // hpp[2][128][128]

// Hierarchical barrier state: one 64B line per counter/watermark.
// Monotonic (never reset) => no reset/reorder race; episode = cnt>>4.
__device__ __align__(64) unsigned g_gcnt[16][16];
__device__ __align__(64) unsigned g_ggen[16][16];
__device__ __align__(64) unsigned g_rcnt[16];
__device__ __align__(64) unsigned g_rgen[16];

__device__ __forceinline__ float sigm(float v){ return 1.0f/(1.0f+expf(-v)); }

// Cross-workgroup data: system-scope relaxed atomics => sc0 sc1 accesses,
// coherent at the Infinity Cache; no fence lowering is load-bearing for data.
__device__ __forceinline__ float gload(const float* p){
  return __hip_atomic_load(p, __ATOMIC_RELAXED, __HIP_MEMORY_SCOPE_SYSTEM);
}
__device__ __forceinline__ void gstore(float* p, float v){
  __hip_atomic_store(p, v, __ATOMIC_RELAXED, __HIP_MEMORY_SCOPE_SYSTEM);
}

// Two-level generation barrier: 16 groups x 16 blocks. Each line sees at most
// 16 RMWs + 15 pollers per episode (vs 256 RMWs + 255 pollers on one line).
__device__ __forceinline__ void gsync(int w){
  __syncthreads();
  if (threadIdx.x == 0) {
    asm volatile("" ::: "memory");
    const int g = w >> 4;
    unsigned prev = __hip_atomic_fetch_add(&g_gcnt[g][0], 1u, __ATOMIC_RELAXED, __HIP_MEMORY_SCOPE_SYSTEM);
    unsigned ep   = prev >> 4;               // barrier episode
    if ((prev & 15u) == 15u) {
      // last arrival of this group -> arrive at root
      unsigned rprev = __hip_atomic_fetch_add(&g_rcnt[0], 1u, __ATOMIC_RELAXED, __HIP_MEMORY_SCOPE_SYSTEM);
      if ((rprev & 15u) == 15u) {
        __hip_atomic_store(&g_rgen[0], (rprev >> 4) + 1u, __ATOMIC_RELEASE, __HIP_MEMORY_SCOPE_SYSTEM);
      } else {
        while ((int)(__hip_atomic_load(&g_rgen[0], __ATOMIC_RELAXED, __HIP_MEMORY_SCOPE_SYSTEM) - (ep + 1u)) < 0)
          __builtin_amdgcn_s_sleep(1);
      }
      __hip_atomic_store(&g_ggen[g][0], ep + 1u, __ATOMIC_RELEASE, __HIP_MEMORY_SCOPE_SYSTEM);
    } else {
      while ((int)(__hip_atomic_load(&g_ggen[g][0], __ATOMIC_RELAXED, __HIP_MEMORY_SCOPE_SYSTEM) - (ep + 1u)) < 0)
        __builtin_amdgcn_s_sleep(1);
    }
    asm volatile("" ::: "memory");
  }
  __syncthreads();
}

// Partial GEMV over this wave's k-slice: NGR groups of 8 k, depth-6 prefetch
// (48 loads in flight -> IF latency/6 ~ 150cy < 256cy FMA per group).
#define PFD 6
#define GEMM_BODY(NGR, DEC, SRC, WR, DWP)                                     \
  {                                                                           \
    float pv[PFD][8];                                                         \
    _Pragma("unroll")                                                         \
    for (int d=0; d<PFD; ++d) {                                               \
      _Pragma("unroll")                                                       \
      for (int u=0; u<8; ++u) pv[d][u] = gload((SRC) + (d*8+u)*Bc);           \
    }                                                                         \
    _Pragma("unroll")                                                         \
    for (int it=0; it<(NGR); ++it) {                                          \
      const int cb = it % PFD;                                                \
      _Pragma("unroll")                                                       \
      for (int u=0; u<8; ++u) {                                               \
        const int kk = it*8+u;                                                \
        float hv = pv[cb][u];                                                 \
        _Pragma("unroll")                                                     \
        for (int r=0; r<16; ++r) part[r] = fmaf(hv, (WR)[r][kk], part[r]);    \
        if (DEC) dacc = fmaf(hv, (DWP)[kk], dacc);                            \
      }                                                                       \
      if (it+PFD < (NGR)) {                                                   \
        _Pragma("unroll")                                                     \
        for (int u=0; u<8; ++u) pv[cb][u] = gload((SRC) + ((it+PFD)*8+u)*Bc); \
      }                                                                       \
    }                                                                         \
  }

__global__ __launch_bounds__(TPB, 2) void act_lstm_kernel(
    const float* __restrict__ x,   const float* __restrict__ Wih,
    const float* __restrict__ Whh, const float* __restrict__ bih,
    const float* __restrict__ bhh, const float* __restrict__ hw,
    const float* __restrict__ hbp, const float* __restrict__ dw,
    const float* __restrict__ db,  float* __restrict__ out,
    float* __restrict__ ws)
{
  const int w    = blockIdx.x;
  const int tid  = threadIdx.x;
  const int lane = tid & 63;
  const int wid  = __builtin_amdgcn_readfirstlane(tid >> 6);
  const int gs   = w >> 1;          // j-group [0,128): owns j = gs*4..+3
  const int bh   = w & 1;           // batch half
  const int b    = bh*64 + lane;
  const int jb   = gs*4;
  const int jmine= jb + wid;
  const int jrow = jmine * Bc;
  const int kq   = wid * 128;       // k-quarter for h-GEMV
  const int iq   = wid * 64;        // i-quarter for x-GEMV
  const int nc   = gs & 15;         // decoder class for w<32 blocks

  float* xs   = ws + XS_OFF;
  float* hbuf = ws + HB_OFF;
  float* stc  = ws + SC_OFF;
  float* hpp  = ws + HP_OFF;

  __shared__ float lds_red[4*16*64];
  __shared__ float lds_hp[4*64];
  __shared__ float lds_hq[2*128];
  __shared__ float lds_pmh[128];
  __shared__ float lds_dec[4*64];
  __shared__ unsigned lds_u[2];

  const float* whp[16];
  const float* wip[16];
  float bsum[4];
  #pragma unroll
  for (int r=0; r<16; ++r) {
    const int grow = (r>>2)*512 + jb + (r&3);
    whp[r] = Whh + grow*Hc + kq;
    wip[r] = Wih + grow*Ic + iq;
  }
  #pragma unroll
  for (int ty=0; ty<4; ++ty) bsum[ty] = bih[ty*512 + jmine] + bhh[ty*512 + jmine];
  const float hwj = hw[jmine];
  const float hb0 = hbp[0];
  const float* dwq = dw + nc*Hc + kq;
  const float dbv  = db[nc];

  // -------- prologue: stage x[:,:,0] into xs[0][i][b] --------
  {
    int g = w*TPB + tid;
    if (g < XSZ) {
      int i = g >> 7, bb = g & 127;
      gstore(xs + i*Bc + bb, x[bb*(Ic*Tc) + i*Tc + 0]);
    }
  }
  gsync(w);

  // -------- persistent state --------
  float c = 0.f;
  float st_run=0.f, ct_run=0.f, prev_pm=0.f;
  float cumw=0.f, prevw=0.f, ntfw=0.f, rtvw=0.f, psumw=0.f;  // waves 0,1: b'=wid*64+lane
  bool  ntsetw=false;
  int   gt = 0;
  int   lastpar = 0;

  for (int t=0; t<Tc; ++t) {
    float xg[4];
    for (int mm=0;; ++mm) {
      float part[16];
      #pragma unroll
      for (int r=0; r<16; ++r) part[r]=0.f;
      float dacc = 0.f;

      // ---------- phase A: GEMVs ----------
      if (mm == 0) {
        const float* xsr = xs + (t&1)*XSZ + iq*Bc + b;
        GEMM_BODY(8, false, xsr, wip, dwq)
        #pragma unroll
        for (int r=0; r<16; ++r) lds_red[wid*1024 + r*64 + lane] = part[r];
        __syncthreads();
        #pragma unroll
        for (int ty=0; ty<4; ++ty) {
          float a0 = lds_red[0*1024 + (ty*4+wid)*64 + lane];
          float a1 = lds_red[1*1024 + (ty*4+wid)*64 + lane];
          float a2 = lds_red[2*1024 + (ty*4+wid)*64 + lane];
          float a3 = lds_red[3*1024 + (ty*4+wid)*64 + lane];
          xg[ty] = bsum[ty] + ((a0+a1)+(a2+a3));
        }
        __syncthreads();   // before lds_red reuse

        // stage next timestep's x slice (hidden under GEMV)
        if (t+1 < Tc) {
          int g = w*TPB + tid;
          if (g < XSZ) {
            int i = g >> 7, bb = g & 127;
            gstore(xs + ((t+1)&1)*XSZ + i*Bc + bb, x[bb*(Ic*Tc) + i*Tc + (t+1)]);
          }
        }

        #pragma unroll
        for (int r=0; r<16; ++r) part[r]=0.f;
        if (t > 0) {
          const float* hs = stc + lastpar*HSZ + kq*Bc + b;
          bool isdec = (w < 32);
          GEMM_BODY(16, isdec, hs, whp, dwq)
        }
      } else {
        const float* hs = hbuf + ((gt-1)&1)*HSZ + kq*Bc + b;
        GEMM_BODY(16, false, hs, whp, dwq)
      }

      // ---------- reduce partials across waves ----------
      #pragma unroll
      for (int r=0; r<16; ++r) lds_red[wid*1024 + r*64 + lane] = part[r];
      if (mm==0 && t>0 && w<32) lds_dec[wid*64+lane] = dacc;
      __syncthreads();
      float hacc[4];
      #pragma unroll
      for (int ty=0; ty<4; ++ty) {
        float a0 = lds_red[0*1024 + (ty*4+wid)*64 + lane];
        float a1 = lds_red[1*1024 + (ty*4+wid)*64 + lane];
        float a2 = lds_red[2*1024 + (ty*4+wid)*64 + lane];
        float a3 = lds_red[3*1024 + (ty*4+wid)*64 + lane];
        hacc[ty] = (a0+a1)+(a2+a3);
      }
      if (mm==0 && t>0 && w<32 && wid==0) {
        float y = ((lds_dec[lane]+lds_dec[64+lane])+(lds_dec[128+lane]+lds_dec[192+lane])) + dbv;
        out[(b*NCc + nc)*Tc + (t-1)] = y;
      }

      // ---------- LSTM cell (torch gate order i,f,g,o) ----------
      float ig = sigm(xg[0]+hacc[0]);
      float fg = sigm(xg[1]+hacc[1]);
      float gg = tanhf(xg[2]+hacc[2]);
      float og = sigm(xg[3]+hacc[3]);
      float cn = fg*c + ig*gg;
      float hn = og*tanhf(cn);

      gstore(hbuf + (gt&1)*HSZ + jrow + b, hn);
      gstore(stc  + (gt&1)*HSZ + jrow + b, st_run + (1.f - prev_pm)*hn); // st-candidate
      lds_hp[wid*64+lane] = hn*hwj;
      __syncthreads();
      if (wid == 0) {
        float h4 = (lds_hp[lane]+lds_hp[64+lane])+(lds_hp[128+lane]+lds_hp[192+lane]);
        gstore(hpp + (gt&1)*PSZ + gs*Bc + b, h4);
      }

      gsync(w);

      // ---------- phase B: replicated halting decision ----------
      {
        const int bh2 = wid & 1, gq = wid >> 1;
        const float* hp = hpp + (gt&1)*PSZ + gq*64*Bc + bh2*64 + lane;
        float s[8];
        #pragma unroll
        for (int u=0; u<8; ++u) s[u]=0.f;
        #pragma unroll
        for (int g8=0; g8<8; ++g8) {
          #pragma unroll
          for (int u=0; u<8; ++u) s[u] += gload(hp + (g8*8+u)*Bc);
        }
        lds_hq[gq*128 + bh2*64 + lane] = ((s[0]+s[1])+(s[2]+s[3]))+((s[4]+s[5])+(s[6]+s[7]));
      }
      __syncthreads();
      if (wid < 2) {
        float hpv = lds_hq[wid*64+lane] + lds_hq[128 + wid*64+lane];
        float pn = sigm(hpv + hb0);
        cumw += pn;
        int ok = __all(cumw >= 0.99f) ? 1 : 0;
        if (lane == 0) lds_u[wid] = (unsigned)ok;
        lds_pmh[wid*64+lane] = fminf(1.f, cumw);
      }
      __syncthreads();
      int finv = (((lds_u[0] & lds_u[1]) != 0u) || (mm == Mc-1)) ? 1 : 0;

      if (wid < 2) {   // nt/rt tracking for b' = wid*64+lane (replicated)
        float pmf = finv ? 1.f : fminf(1.f, cumw);
        if (!ntsetw && pmf >= 1.f) {
          ntfw = (float)mm;
          rtvw = (mm == 0) ? 0.f : (1.f - prevw);
          ntsetw = true;
        }
        prevw = pmf;
      }
      float pm = finv ? 1.f : lds_pmh[bh*64+lane];
      float ph = pm - prev_pm;
      st_run += ph*hn;
      ct_run += ph*cn;
      prev_pm = pm;
      if (finv) {
        c = ct_run;
        if (wid < 2) {
          psumw += ntfw + rtvw;
          if (w == 0) out[N_OFF + (wid*64+lane)*Tc + t] = ntfw;
          ntsetw=false; prevw=0.f; cumw=0.f; ntfw=0.f; rtvw=0.f;
        }
        st_run=0.f; ct_run=0.f; prev_pm=0.f;
        lastpar = gt & 1;
        ++gt;
        break;
      }
      c = cn;
      ++gt;
    }
  }

  // -------- epilogue: Y for t=23, P --------
  if (w < 32) {
    float da = 0.f;
    const float* hs = stc + lastpar*HSZ + kq*Bc + b;
    #pragma unroll
    for (int kk=0; kk<128; ++kk) da = fmaf(gload(hs + kk*Bc), dwq[kk], da);
    __syncthreads();
    lds_dec[wid*64+lane] = da;
    __syncthreads();
    if (wid == 0) {
      float y = ((lds_dec[lane]+lds_dec[64+lane])+(lds_dec[128+lane]+lds_dec[192+lane])) + dbv;
      out[(b*NCc + nc)*Tc + (Tc-1)] = y;
    }
  }
  if (w == 0 && wid < 2) out[P_OFF + wid*64 + lane] = psumw;
}

extern "C" void kernel_launch(void* const* d_in, const int* in_sizes, int n_in,
                              void* d_out, int out_size, void* d_ws, size_t ws_size,
                              hipStream_t stream) {
  const float* x   = (const float*)d_in[0];
  const float* Wih = (const float*)d_in[1];
  const float* Whh = (const float*)d_in[2];
  const float* bih = (const float*)d_in[3];
  const float* bhh = (const float*)d_in[4];
  const float* hw  = (const float*)d_in[5];
  const float* hb  = (const float*)d_in[6];
  const float* dwp = (const float*)d_in[7];
  const float* dbp = (const float*)d_in[8];
  float* out = (float*)d_out;
  float* ws  = (float*)d_ws;

  void* kargs[] = {(void*)&x, (void*)&Wih, (void*)&Whh, (void*)&bih, (void*)&bhh,
                   (void*)&hw, (void*)&hb, (void*)&dwp, (void*)&dbp, (void*)&out, (void*)&ws};
  hipLaunchCooperativeKernel((void*)act_lstm_kernel, dim3(NWG), dim3(TPB),
                             kargs, 0, stream);
}

// Round 5
// 4524.729 us; speedup vs baseline: 3.1779x; 1.4401x over previous
//
#include <hip/hip_runtime.h>
#include <math.h>

#define NWG 128
#define TPB 1024

static constexpr int Bc=128, Ic=256, Hc=512, NCc=16, Tc=24, Mc=14;
static constexpr int Y_SZ  = Bc*NCc*Tc;     // 49152
static constexpr int P_OFF = Y_SZ;          // 49152
static constexpr int N_OFF = Y_SZ + Bc;     // 49280

// ws layout (floats) -- total 360448 floats = 1.375 MiB (r4-proven budget)
static constexpr int XSZ    = Ic*Bc;                 // 32768
static constexpr int HSZ    = Hc*Bc;                 // 65536
static constexpr int PSZ    = Bc*Bc;                 // 16384 (hpp: 128 blocks x 128 b)
static constexpr int XS_OFF = 0;                     // xs[2][256][128]
static constexpr int HB_OFF = XS_OFF + 2*XSZ;        // hbuf[2][512][128]
static constexpr int SC_OFF = HB_OFF + 2*HSZ;        // stc[2][512][128]
static constexpr int HP_OFF = SC_OFF + 2*HSZ;        // hpp[2][128][128]

// Hierarchical barrier: 16 groups x 8 blocks; monotonic watermarks, 64B lines.
__device__ __align__(64) unsigned g_bcnt[16][16];
__device__ __align__(64) unsigned g_bgen[16][16];
__device__ __align__(64) unsigned g_brc[16];
__device__ __align__(64) unsigned g_brg[16];

__device__ __forceinline__ float sigm(float v){ return 1.0f/(1.0f+expf(-v)); }

__device__ __forceinline__ float gload(const float* p){
  return __hip_atomic_load(p, __ATOMIC_RELAXED, __HIP_MEMORY_SCOPE_SYSTEM);
}
__device__ __forceinline__ void gstore(float* p, float v){
  __hip_atomic_store(p, v, __ATOMIC_RELAXED, __HIP_MEMORY_SCOPE_SYSTEM);
}

__device__ __forceinline__ void gsync(int w){
  __syncthreads();
  if (threadIdx.x == 0) {
    asm volatile("" ::: "memory");
    const int g = w >> 3;                    // 16 groups of 8
    unsigned prev = __hip_atomic_fetch_add(&g_bcnt[g][0], 1u, __ATOMIC_RELAXED, __HIP_MEMORY_SCOPE_SYSTEM);
    unsigned ep   = prev >> 3;               // barrier episode
    if ((prev & 7u) == 7u) {
      unsigned rprev = __hip_atomic_fetch_add(&g_brc[0], 1u, __ATOMIC_RELAXED, __HIP_MEMORY_SCOPE_SYSTEM);
      if ((rprev & 15u) == 15u) {
        __hip_atomic_store(&g_brg[0], (rprev >> 4) + 1u, __ATOMIC_RELEASE, __HIP_MEMORY_SCOPE_SYSTEM);
      } else {
        while ((int)(__hip_atomic_load(&g_brg[0], __ATOMIC_RELAXED, __HIP_MEMORY_SCOPE_SYSTEM) - (ep + 1u)) < 0)
          __builtin_amdgcn_s_sleep(1);
      }
      __hip_atomic_store(&g_bgen[g][0], ep + 1u, __ATOMIC_RELEASE, __HIP_MEMORY_SCOPE_SYSTEM);
    } else {
      while ((int)(__hip_atomic_load(&g_bgen[g][0], __ATOMIC_RELAXED, __HIP_MEMORY_SCOPE_SYSTEM) - (ep + 1u)) < 0)
        __builtin_amdgcn_s_sleep(1);
    }
    asm volatile("" ::: "memory");
  }
  __syncthreads();
}

// Partial GEMV over this wave's slice: NGR groups of 8, depth-4 prefetch,
// 16 gate rows. dacc always accumulated (harmless when unused).
#define PFD 4
#define GEMM_BODY(NGR, SRC, WR, DWP)                                          \
  {                                                                           \
    float pv[PFD][8];                                                         \
    _Pragma("unroll")                                                         \
    for (int d=0; d<PFD && d<(NGR); ++d) {                                    \
      _Pragma("unroll")                                                       \
      for (int u=0; u<8; ++u) pv[d][u] = gload((SRC) + (d*8+u)*Bc);           \
    }                                                                         \
    _Pragma("unroll")                                                         \
    for (int it=0; it<(NGR); ++it) {                                          \
      const int cb = it % PFD;                                                \
      _Pragma("unroll")                                                       \
      for (int u=0; u<8; ++u) {                                               \
        const int kk = it*8+u;                                                \
        float hv = pv[cb][u];                                                 \
        _Pragma("unroll")                                                     \
        for (int r=0; r<16; ++r) part[r] = fmaf(hv, (WR)[r][kk], part[r]);    \
        dacc = fmaf(hv, (DWP)[kk], dacc);                                     \
      }                                                                       \
      if (it+PFD < (NGR)) {                                                   \
        _Pragma("unroll")                                                     \
        for (int u=0; u<8; ++u) pv[cb][u] = gload((SRC) + ((it+PFD)*8+u)*Bc); \
      }                                                                       \
    }                                                                         \
  }

__global__ __launch_bounds__(TPB, 1) void act_lstm_kernel(
    const float* __restrict__ x,   const float* __restrict__ Wih,
    const float* __restrict__ Whh, const float* __restrict__ bih,
    const float* __restrict__ bhh, const float* __restrict__ hw,
    const float* __restrict__ hbp, const float* __restrict__ dw,
    const float* __restrict__ db,  float* __restrict__ out,
    float* __restrict__ ws)
{
  const int w    = blockIdx.x;
  const int tid  = threadIdx.x;
  const int lane = tid & 63;
  const int wid  = __builtin_amdgcn_readfirstlane(tid >> 6); // 0..15
  const int bh   = wid & 1;
  const int k8   = wid >> 1;         // 0..7 : k-eighth (h) / i-eighth (x)
  const int b    = bh*64 + lane;
  const int jb   = w * 4;            // block owns j = jb..jb+3
  const int jpair= k8 & 3;           // cell ownership for wid<8
  const int jmine= jb + jpair;       // valid for wid<8
  const int kq   = k8 * 64;          // h/st k-slice base
  const int iq   = k8 * 32;          // x i-slice base
  const bool cellw = (wid < 8);

  float* xs   = ws + XS_OFF;
  float* hbuf = ws + HB_OFF;
  float* stc  = ws + SC_OFF;
  float* hpp  = ws + HP_OFF;

  __shared__ float lds_red[8*8*128];   // [k8][row-chunk 8][b] = 32 KB
  __shared__ float lds_hp[4*128];
  __shared__ float lds_hq[8*128];
  __shared__ float lds_pmh[128];
  __shared__ float lds_dec[8*128];
  __shared__ unsigned lds_u[2];

  // uniform weight row pointers: 16 rows, grow = ty*512 + jb + jj
  const float* whp[16];
  const float* wip[16];
  #pragma unroll
  for (int r=0; r<16; ++r) {
    const int grow = (r>>2)*512 + jb + (r&3);
    whp[r] = Whh + grow*Hc + kq;
    wip[r] = Wih + grow*Ic + iq;
  }
  float bsum[4];
  #pragma unroll
  for (int ty=0; ty<4; ++ty) bsum[ty] = bih[ty*512 + jmine] + bhh[ty*512 + jmine];
  const float hwj = hw[jmine];
  const float hb0 = hbp[0];
  const float* dwq = dw + (w < NCc ? w : 0)*Hc + kq;   // decoder class = w for w<16
  const float dbv  = db[w < NCc ? w : 0];

  // -------- prologue: stage x[:,:,0] --------
  if (tid < 256) {
    int g = w*256 + tid;             // 128*256 = 32768 = XSZ
    int i = g >> 7, bb = g & 127;
    gstore(xs + i*Bc + bb, x[bb*(Ic*Tc) + i*Tc + 0]);
  }
  gsync(w);

  // -------- persistent state --------
  float c = 0.f;                      // cell (jmine, b) for wid<8
  float st_run=0.f, ct_run=0.f, prev_pm=0.f;
  float cumw=0.f, prevw=0.f, ntfw=0.f, rtvw=0.f, psumw=0.f;  // wid<2: b'=wid*64+lane
  bool  ntsetw=false;
  int   gt = 0;
  int   lastpar = 0;

  for (int t=0; t<Tc; ++t) {
    float xg[4];
    for (int mm=0;; ++mm) {
      float part[16];
      float hacc[4];
      float dacc = 0.f;

      // ---------- phase A ----------
      if (mm == 0) {
        // x-GEMV
        #pragma unroll
        for (int r=0; r<16; ++r) part[r]=0.f;
        {
          const float* xsr = xs + (t&1)*XSZ + iq*Bc + b;
          GEMM_BODY(4, xsr, wip, dwq)
        }
        dacc = 0.f;
        // reduce x partials, 2 chunks of 8 rows
        #pragma unroll
        for (int ch=0; ch<2; ++ch) {
          #pragma unroll
          for (int rr=0; rr<8; ++rr) lds_red[(k8*8+rr)*128 + b] = part[ch*8+rr];
          __syncthreads();
          if (cellw) {
            #pragma unroll
            for (int tt=0; tt<2; ++tt) {
              const int ty = ch*2+tt;
              const int rr = (ty*4+jpair) & 7;
              float s=0.f;
              #pragma unroll
              for (int kk8=0; kk8<8; ++kk8) s += lds_red[(kk8*8+rr)*128 + b];
              xg[ty] = bsum[ty] + s;
            }
          }
          __syncthreads();
        }
        // stage next timestep's x slice
        if (t+1 < Tc && tid < 256) {
          int g = w*256 + tid;
          int i = g >> 7, bb = g & 127;
          gstore(xs + ((t+1)&1)*XSZ + i*Bc + bb, x[bb*(Ic*Tc) + i*Tc + (t+1)]);
        }
        // st-GEMV (h_prev = st(t-1)); also decoder dot for w<16
        #pragma unroll
        for (int r=0; r<16; ++r) part[r]=0.f;
        if (t > 0) {
          const float* hs = stc + lastpar*HSZ + kq*Bc + b;
          GEMM_BODY(8, hs, whp, dwq)
        }
      } else {
        #pragma unroll
        for (int r=0; r<16; ++r) part[r]=0.f;
        const float* hs = hbuf + ((gt-1)&1)*HSZ + kq*Bc + b;
        GEMM_BODY(8, hs, whp, dwq)
      }

      // ---------- reduce h/st partials (2 chunks), + decoder ----------
      if (mm == 0) lds_dec[k8*128 + b] = dacc;
      #pragma unroll
      for (int ch=0; ch<2; ++ch) {
        #pragma unroll
        for (int rr=0; rr<8; ++rr) lds_red[(k8*8+rr)*128 + b] = part[ch*8+rr];
        __syncthreads();
        if (cellw) {
          #pragma unroll
          for (int tt=0; tt<2; ++tt) {
            const int ty = ch*2+tt;
            const int rr = (ty*4+jpair) & 7;
            float s=0.f;
            #pragma unroll
            for (int kk8=0; kk8<8; ++kk8) s += lds_red[(kk8*8+rr)*128 + b];
            hacc[ty] = s;
          }
        }
        __syncthreads();
      }
      if (mm==0 && t>0 && w<NCc && wid<2) {
        const int b2 = wid*64+lane;
        float y=0.f;
        #pragma unroll
        for (int q=0; q<8; ++q) y += lds_dec[q*128 + b2];
        out[(b2*NCc + w)*Tc + (t-1)] = y + dbv;
      }

      // ---------- LSTM cell (i,f,g,o) ----------
      float hn=0.f, cn=0.f;
      if (cellw) {
        float ig = sigm(xg[0]+hacc[0]);
        float fg = sigm(xg[1]+hacc[1]);
        float gg = tanhf(xg[2]+hacc[2]);
        float og = sigm(xg[3]+hacc[3]);
        cn = fg*c + ig*gg;
        hn = og*tanhf(cn);
        gstore(hbuf + (gt&1)*HSZ + jmine*Bc + b, hn);
        gstore(stc  + (gt&1)*HSZ + jmine*Bc + b, st_run + (1.f - prev_pm)*hn);
        lds_hp[jpair*128 + b] = hn*hwj;
      }
      __syncthreads();
      if (wid < 2) {
        const int b2 = wid*64+lane;
        float h4 = (lds_hp[b2]+lds_hp[128+b2])+(lds_hp[256+b2]+lds_hp[384+b2]);
        gstore(hpp + (gt&1)*PSZ + w*Bc + b2, h4);
      }

      gsync(w);

      // ---------- phase B: replicated halting decision ----------
      {
        const int q = wid >> 1, bh2 = wid & 1;
        const int b2 = bh2*64 + lane;
        const float* hp = hpp + (gt&1)*PSZ + q*16*Bc + b2;
        float s0=0.f, s1=0.f, s2=0.f, s3=0.f;
        #pragma unroll
        for (int i4=0; i4<16; i4+=4) {
          s0 += gload(hp + (i4+0)*Bc);
          s1 += gload(hp + (i4+1)*Bc);
          s2 += gload(hp + (i4+2)*Bc);
          s3 += gload(hp + (i4+3)*Bc);
        }
        lds_hq[q*128 + b2] = (s0+s1)+(s2+s3);
      }
      __syncthreads();
      if (wid < 2) {
        const int b2 = wid*64+lane;
        float hpv=0.f;
        #pragma unroll
        for (int q=0; q<8; ++q) hpv += lds_hq[q*128 + b2];
        float pn = sigm(hpv + hb0);
        cumw += pn;
        int ok = __all(cumw >= 0.99f) ? 1 : 0;
        if (lane == 0) lds_u[wid] = (unsigned)ok;
        lds_pmh[b2] = fminf(1.f, cumw);
      }
      __syncthreads();
      int finv = (((lds_u[0] & lds_u[1]) != 0u) || (mm == Mc-1)) ? 1 : 0;

      if (wid < 2) {
        float pmf = finv ? 1.f : fminf(1.f, cumw);
        if (!ntsetw && pmf >= 1.f) {
          ntfw = (float)mm;
          rtvw = (mm == 0) ? 0.f : (1.f - prevw);
          ntsetw = true;
        }
        prevw = pmf;
      }
      if (cellw) {
        float pm = finv ? 1.f : lds_pmh[b];
        float ph = pm - prev_pm;
        st_run += ph*hn;
        ct_run += ph*cn;
        prev_pm = pm;
        c = finv ? ct_run : cn;
      }
      if (finv) {
        if (wid < 2) {
          psumw += ntfw + rtvw;
          if (w == 0) out[N_OFF + (wid*64+lane)*Tc + t] = ntfw;
          ntsetw=false; prevw=0.f; cumw=0.f; ntfw=0.f; rtvw=0.f;
        }
        if (cellw) { st_run=0.f; ct_run=0.f; prev_pm=0.f; }
        lastpar = gt & 1;
        ++gt;
        break;
      }
      ++gt;
    }
  }

  // -------- epilogue: Y for t=23, P --------
  if (w < NCc) {
    float da = 0.f;
    const float* hs = stc + lastpar*HSZ + kq*Bc + b;
    #pragma unroll
    for (int kk=0; kk<64; ++kk) da = fmaf(gload(hs + kk*Bc), dwq[kk], da);
    __syncthreads();
    lds_dec[k8*128 + b] = da;
    __syncthreads();
    if (wid < 2) {
      const int b2 = wid*64+lane;
      float y=0.f;
      #pragma unroll
      for (int q=0; q<8; ++q) y += lds_dec[q*128 + b2];
      out[(b2*NCc + w)*Tc + (Tc-1)] = y + dbv;
    }
  }
  if (w == 20 && wid < 2) out[P_OFF + wid*64 + lane] = psumw;
}

extern "C" void kernel_launch(void* const* d_in, const int* in_sizes, int n_in,
                              void* d_out, int out_size, void* d_ws, size_t ws_size,
                              hipStream_t stream) {
  const float* x   = (const float*)d_in[0];
  const float* Wih = (const float*)d_in[1];
  const float* Whh = (const float*)d_in[2];
  const float* bih = (const float*)d_in[3];
  const float* bhh = (const float*)d_in[4];
  const float* hw  = (const float*)d_in[5];
  const float* hb  = (const float*)d_in[6];
  const float* dwp = (const float*)d_in[7];
  const float* dbp = (const float*)d_in[8];
  float* out = (float*)d_out;
  float* ws  = (float*)d_ws;

  void* kargs[] = {(void*)&x, (void*)&Wih, (void*)&Whh, (void*)&bih, (void*)&bhh,
                   (void*)&hw, (void*)&hb, (void*)&dwp, (void*)&dbp, (void*)&out, (void*)&ws};
  hipLaunchCooperativeKernel((void*)act_lstm_kernel, dim3(NWG), dim3(TPB),
                             kargs, 0, stream);
}

// Round 6
// 3131.109 us; speedup vs baseline: 4.5924x; 1.4451x over previous
//
#include <hip/hip_runtime.h>
#include <math.h>

#define NWG 128
#define TPB 1024

static constexpr int Bc=128, Ic=256, Hc=512, NCc=16, Tc=24, Mc=14;
static constexpr int Y_SZ  = Bc*NCc*Tc;     // 49152
static constexpr int P_OFF = Y_SZ;          // 49152
static constexpr int N_OFF = Y_SZ + Bc;     // 49280

// ws layout (floats) -- total 360448 floats = 1.375 MiB (proven budget)
static constexpr int XSZ    = Ic*Bc;                 // 32768
static constexpr int HSZ    = Hc*Bc;                 // 65536
static constexpr int PSZ    = Bc*Bc;                 // 16384
static constexpr int XS_OFF = 0;                     // xs[2][256][128]
static constexpr int HB_OFF = XS_OFF + 2*XSZ;        // hbuf[2][512][128]
static constexpr int SC_OFF = HB_OFF + 2*HSZ;        // stc[2][512][128]
static constexpr int HP_OFF = SC_OFF + 2*HSZ;        // hpp[2][128][128]

// Hierarchical barrier: 16 groups x 8 blocks; monotonic watermarks, 64B lines.
__device__ __align__(64) unsigned g_bcnt[16][16];
__device__ __align__(64) unsigned g_bgen[16][16];
__device__ __align__(64) unsigned g_brc[16];
__device__ __align__(64) unsigned g_brg[16];

__device__ __forceinline__ float sigm(float v){ return 1.0f/(1.0f+expf(-v)); }

// PRODUCER side: system-scope write-through stores (sc0 sc1) -> data lands at
// the coherent Infinity Cache before the barrier (vmcnt drained at barrier).
__device__ __forceinline__ void gstore(float* p, float v){
  __hip_atomic_store(p, v, __ATOMIC_RELAXED, __HIP_MEMORY_SCOPE_SYSTEM);
}

// Barrier + CONSUMER-side acquire: after the generation barrier, one
// agent-scope acquire fence invalidates L1 + per-XCD L2, so subsequent PLAIN
// cached loads of cross-block data miss to the coherent IF and then pipeline
// normally (clusterable, batched vmcnt) -- unlike serialized atomic loads.
__device__ __forceinline__ void gsync(int w){
  __syncthreads();
  if (threadIdx.x == 0) {
    asm volatile("" ::: "memory");
    const int g = w >> 3;                    // 16 groups of 8
    unsigned prev = __hip_atomic_fetch_add(&g_bcnt[g][0], 1u, __ATOMIC_RELAXED, __HIP_MEMORY_SCOPE_SYSTEM);
    unsigned ep   = prev >> 3;               // barrier episode
    if ((prev & 7u) == 7u) {
      unsigned rprev = __hip_atomic_fetch_add(&g_brc[0], 1u, __ATOMIC_RELAXED, __HIP_MEMORY_SCOPE_SYSTEM);
      if ((rprev & 15u) == 15u) {
        __hip_atomic_store(&g_brg[0], (rprev >> 4) + 1u, __ATOMIC_RELEASE, __HIP_MEMORY_SCOPE_SYSTEM);
      } else {
        while ((int)(__hip_atomic_load(&g_brg[0], __ATOMIC_RELAXED, __HIP_MEMORY_SCOPE_SYSTEM) - (ep + 1u)) < 0)
          __builtin_amdgcn_s_sleep(1);
      }
      __hip_atomic_store(&g_bgen[g][0], ep + 1u, __ATOMIC_RELEASE, __HIP_MEMORY_SCOPE_SYSTEM);
    } else {
      while ((int)(__hip_atomic_load(&g_bgen[g][0], __ATOMIC_RELAXED, __HIP_MEMORY_SCOPE_SYSTEM) - (ep + 1u)) < 0)
        __builtin_amdgcn_s_sleep(1);
    }
    asm volatile("" ::: "memory");
  }
  __syncthreads();
  __builtin_amdgcn_fence(__ATOMIC_ACQUIRE, "agent");   // inv L1 + XCD L2
}

// Partial GEMV over this wave's slice: NGR groups of 8, depth-4 software
// prefetch with PLAIN loads (compiler clusters + batches waitcnt).
#define PFD 4
#define GEMM_BODY(NGR, SRC, WR, DWP)                                          \
  {                                                                           \
    float pv[PFD][8];                                                         \
    _Pragma("unroll")                                                         \
    for (int d=0; d<PFD && d<(NGR); ++d) {                                    \
      _Pragma("unroll")                                                       \
      for (int u=0; u<8; ++u) pv[d][u] = (SRC)[(d*8+u)*Bc];                   \
    }                                                                         \
    _Pragma("unroll")                                                         \
    for (int it=0; it<(NGR); ++it) {                                          \
      const int cb = it % PFD;                                                \
      _Pragma("unroll")                                                       \
      for (int u=0; u<8; ++u) {                                               \
        const int kk = it*8+u;                                                \
        float hv = pv[cb][u];                                                 \
        _Pragma("unroll")                                                     \
        for (int r=0; r<16; ++r) part[r] = fmaf(hv, (WR)[r][kk], part[r]);    \
        dacc = fmaf(hv, (DWP)[kk], dacc);                                     \
      }                                                                       \
      if (it+PFD < (NGR)) {                                                   \
        _Pragma("unroll")                                                     \
        for (int u=0; u<8; ++u) pv[cb][u] = (SRC)[((it+PFD)*8+u)*Bc];         \
      }                                                                       \
    }                                                                         \
  }

__global__ __launch_bounds__(TPB, 1) void act_lstm_kernel(
    const float* __restrict__ x,   const float* __restrict__ Wih,
    const float* __restrict__ Whh, const float* __restrict__ bih,
    const float* __restrict__ bhh, const float* __restrict__ hw,
    const float* __restrict__ hbp, const float* __restrict__ dw,
    const float* __restrict__ db,  float* __restrict__ out,
    float* __restrict__ ws)
{
  const int w    = blockIdx.x;
  const int tid  = threadIdx.x;
  const int lane = tid & 63;
  const int wid  = __builtin_amdgcn_readfirstlane(tid >> 6); // 0..15
  const int bh   = wid & 1;
  const int k8   = wid >> 1;         // 0..7 : k-eighth (h) / i-eighth (x)
  const int b    = bh*64 + lane;
  const int jb   = w * 4;            // block owns j = jb..jb+3
  const int jpair= k8 & 3;           // cell ownership for wid<8
  const int jmine= jb + jpair;       // valid for wid<8
  const int kq   = k8 * 64;          // h/st k-slice base
  const int iq   = k8 * 32;          // x i-slice base
  const bool cellw = (wid < 8);

  float* xs   = ws + XS_OFF;
  float* hbuf = ws + HB_OFF;
  float* stc  = ws + SC_OFF;
  float* hpp  = ws + HP_OFF;

  __shared__ float lds_red[8*8*128];   // [k8][row-chunk 8][b] = 32 KB
  __shared__ float lds_hp[4*128];
  __shared__ float lds_hq[8*128];
  __shared__ float lds_pmh[128];
  __shared__ float lds_dec[8*128];
  __shared__ unsigned lds_u[2];

  const float* whp[16];
  const float* wip[16];
  #pragma unroll
  for (int r=0; r<16; ++r) {
    const int grow = (r>>2)*512 + jb + (r&3);
    whp[r] = Whh + grow*Hc + kq;
    wip[r] = Wih + grow*Ic + iq;
  }
  float bsum[4];
  #pragma unroll
  for (int ty=0; ty<4; ++ty) bsum[ty] = bih[ty*512 + jmine] + bhh[ty*512 + jmine];
  const float hwj = hw[jmine];
  const float hb0 = hbp[0];
  const float* dwq = dw + (w < NCc ? w : 0)*Hc + kq;   // decoder class = w for w<16
  const float dbv  = db[w < NCc ? w : 0];

  // -------- prologue: stage x[:,:,0] --------
  if (tid < 256) {
    int g = w*256 + tid;             // 128*256 = 32768 = XSZ
    int i = g >> 7, bb = g & 127;
    gstore(xs + i*Bc + bb, x[bb*(Ic*Tc) + i*Tc + 0]);
  }
  gsync(w);

  // -------- persistent state --------
  float c = 0.f;                      // cell (jmine, b) for wid<8
  float st_run=0.f, ct_run=0.f, prev_pm=0.f;
  float cumw=0.f, prevw=0.f, ntfw=0.f, rtvw=0.f, psumw=0.f;  // wid<2: b'=wid*64+lane
  bool  ntsetw=false;
  int   gt = 0;
  int   lastpar = 0;

  for (int t=0; t<Tc; ++t) {
    float xg[4];
    for (int mm=0;; ++mm) {
      float part[16];
      float hacc[4];
      float dacc = 0.f;

      // ---------- phase A ----------
      if (mm == 0) {
        // x-GEMV
        #pragma unroll
        for (int r=0; r<16; ++r) part[r]=0.f;
        {
          const float* xsr = xs + (t&1)*XSZ + iq*Bc + b;
          GEMM_BODY(4, xsr, wip, dwq)
        }
        dacc = 0.f;
        // reduce x partials, 2 chunks of 8 rows
        #pragma unroll
        for (int ch=0; ch<2; ++ch) {
          #pragma unroll
          for (int rr=0; rr<8; ++rr) lds_red[(k8*8+rr)*128 + b] = part[ch*8+rr];
          __syncthreads();
          if (cellw) {
            #pragma unroll
            for (int tt=0; tt<2; ++tt) {
              const int ty = ch*2+tt;
              const int rr = (ty*4+jpair) & 7;
              float s=0.f;
              #pragma unroll
              for (int kk8=0; kk8<8; ++kk8) s += lds_red[(kk8*8+rr)*128 + b];
              xg[ty] = bsum[ty] + s;
            }
          }
          __syncthreads();
        }
        // stage next timestep's x slice
        if (t+1 < Tc && tid < 256) {
          int g = w*256 + tid;
          int i = g >> 7, bb = g & 127;
          gstore(xs + ((t+1)&1)*XSZ + i*Bc + bb, x[bb*(Ic*Tc) + i*Tc + (t+1)]);
        }
        // st-GEMV (h_prev = st(t-1)); also decoder dot for w<16
        #pragma unroll
        for (int r=0; r<16; ++r) part[r]=0.f;
        if (t > 0) {
          const float* hs = stc + lastpar*HSZ + kq*Bc + b;
          GEMM_BODY(8, hs, whp, dwq)
        }
      } else {
        #pragma unroll
        for (int r=0; r<16; ++r) part[r]=0.f;
        const float* hs = hbuf + ((gt-1)&1)*HSZ + kq*Bc + b;
        GEMM_BODY(8, hs, whp, dwq)
      }

      // ---------- reduce h/st partials (2 chunks), + decoder ----------
      if (mm == 0) lds_dec[k8*128 + b] = dacc;
      #pragma unroll
      for (int ch=0; ch<2; ++ch) {
        #pragma unroll
        for (int rr=0; rr<8; ++rr) lds_red[(k8*8+rr)*128 + b] = part[ch*8+rr];
        __syncthreads();
        if (cellw) {
          #pragma unroll
          for (int tt=0; tt<2; ++tt) {
            const int ty = ch*2+tt;
            const int rr = (ty*4+jpair) & 7;
            float s=0.f;
            #pragma unroll
            for (int kk8=0; kk8<8; ++kk8) s += lds_red[(kk8*8+rr)*128 + b];
            hacc[ty] = s;
          }
        }
        __syncthreads();
      }
      if (mm==0 && t>0 && w<NCc && wid<2) {
        const int b2 = wid*64+lane;
        float y=0.f;
        #pragma unroll
        for (int q=0; q<8; ++q) y += lds_dec[q*128 + b2];
        out[(b2*NCc + w)*Tc + (t-1)] = y + dbv;
      }

      // ---------- LSTM cell (i,f,g,o) ----------
      float hn=0.f, cn=0.f;
      if (cellw) {
        float ig = sigm(xg[0]+hacc[0]);
        float fg = sigm(xg[1]+hacc[1]);
        float gg = tanhf(xg[2]+hacc[2]);
        float og = sigm(xg[3]+hacc[3]);
        cn = fg*c + ig*gg;
        hn = og*tanhf(cn);
        gstore(hbuf + (gt&1)*HSZ + jmine*Bc + b, hn);
        gstore(stc  + (gt&1)*HSZ + jmine*Bc + b, st_run + (1.f - prev_pm)*hn);
        lds_hp[jpair*128 + b] = hn*hwj;
      }
      __syncthreads();
      if (wid < 2) {
        const int b2 = wid*64+lane;
        float h4 = (lds_hp[b2]+lds_hp[128+b2])+(lds_hp[256+b2]+lds_hp[384+b2]);
        gstore(hpp + (gt&1)*PSZ + w*Bc + b2, h4);
      }

      gsync(w);

      // ---------- phase B: replicated halting decision ----------
      {
        const int q = wid >> 1, bh2 = wid & 1;
        const int b2 = bh2*64 + lane;
        const float* hp = hpp + (gt&1)*PSZ + q*16*Bc + b2;
        float s0=0.f, s1=0.f, s2=0.f, s3=0.f;
        #pragma unroll
        for (int i4=0; i4<16; i4+=4) {
          s0 += hp[(i4+0)*Bc];
          s1 += hp[(i4+1)*Bc];
          s2 += hp[(i4+2)*Bc];
          s3 += hp[(i4+3)*Bc];
        }
        lds_hq[q*128 + b2] = (s0+s1)+(s2+s3);
      }
      __syncthreads();
      if (wid < 2) {
        const int b2 = wid*64+lane;
        float hpv=0.f;
        #pragma unroll
        for (int q=0; q<8; ++q) hpv += lds_hq[q*128 + b2];
        float pn = sigm(hpv + hb0);
        cumw += pn;
        int ok = __all(cumw >= 0.99f) ? 1 : 0;
        if (lane == 0) lds_u[wid] = (unsigned)ok;
        lds_pmh[b2] = fminf(1.f, cumw);
      }
      __syncthreads();
      int finv = (((lds_u[0] & lds_u[1]) != 0u) || (mm == Mc-1)) ? 1 : 0;

      if (wid < 2) {
        float pmf = finv ? 1.f : fminf(1.f, cumw);
        if (!ntsetw && pmf >= 1.f) {
          ntfw = (float)mm;
          rtvw = (mm == 0) ? 0.f : (1.f - prevw);
          ntsetw = true;
        }
        prevw = pmf;
      }
      if (cellw) {
        float pm = finv ? 1.f : lds_pmh[b];
        float ph = pm - prev_pm;
        st_run += ph*hn;
        ct_run += ph*cn;
        prev_pm = pm;
        c = finv ? ct_run : cn;
      }
      if (finv) {
        if (wid < 2) {
          psumw += ntfw + rtvw;
          if (w == 0) out[N_OFF + (wid*64+lane)*Tc + t] = ntfw;
          ntsetw=false; prevw=0.f; cumw=0.f; ntfw=0.f; rtvw=0.f;
        }
        if (cellw) { st_run=0.f; ct_run=0.f; prev_pm=0.f; }
        lastpar = gt & 1;
        ++gt;
        break;
      }
      ++gt;
    }
  }

  // -------- epilogue: Y for t=23, P --------
  if (w < NCc) {
    float da = 0.f;
    const float* hs = stc + lastpar*HSZ + kq*Bc + b;
    #pragma unroll
    for (int kk=0; kk<64; ++kk) da = fmaf(hs[kk*Bc], dwq[kk], da);
    __syncthreads();
    lds_dec[k8*128 + b] = da;
    __syncthreads();
    if (wid < 2) {
      const int b2 = wid*64+lane;
      float y=0.f;
      #pragma unroll
      for (int q=0; q<8; ++q) y += lds_dec[q*128 + b2];
      out[(b2*NCc + w)*Tc + (Tc-1)] = y + dbv;
    }
  }
  if (w == 20 && wid < 2) out[P_OFF + wid*64 + lane] = psumw;
}

extern "C" void kernel_launch(void* const* d_in, const int* in_sizes, int n_in,
                              void* d_out, int out_size, void* d_ws, size_t ws_size,
                              hipStream_t stream) {
  const float* x   = (const float*)d_in[0];
  const float* Wih = (const float*)d_in[1];
  const float* Whh = (const float*)d_in[2];
  const float* bih = (const float*)d_in[3];
  const float* bhh = (const float*)d_in[4];
  const float* hw  = (const float*)d_in[5];
  const float* hb  = (const float*)d_in[6];
  const float* dwp = (const float*)d_in[7];
  const float* dbp = (const float*)d_in[8];
  float* out = (float*)d_out;
  float* ws  = (float*)d_ws;

  void* kargs[] = {(void*)&x, (void*)&Wih, (void*)&Whh, (void*)&bih, (void*)&bhh,
                   (void*)&hw, (void*)&hb, (void*)&dwp, (void*)&dbp, (void*)&out, (void*)&ws};
  hipLaunchCooperativeKernel((void*)act_lstm_kernel, dim3(NWG), dim3(TPB),
                             kargs, 0, stream);
}